// Round 1
// baseline (464.446 us; speedup 1.0000x reference)
//
#include <hip/hip_runtime.h>

#define NB 4096
#define LD 50
#define LC 50
#define LTOT 100
#define DIM 128
#define BIN 16
#define NO 64
#define LN_EPS 1e-5f

__global__ __launch_bounds__(256) void fused_embed_kernel(
    const int* __restrict__ dindex,    // [B,50]
    const int* __restrict__ dmask,     // [B,50]
    const float* __restrict__ cval,    // [B,50]
    const int* __restrict__ cindex,    // [B,50]
    const int* __restrict__ cmask,     // [B,50]
    const float* __restrict__ disc_emb,// [100001,128]
    const float* __restrict__ v_emb,   // [1001,16]
    const float* __restrict__ b1_emb,  // [1001,16]
    const float* __restrict__ w_emb,   // [1001,2048]
    const float* __restrict__ b2_emb,  // [1001,128]
    const float* __restrict__ ln_gamma,// [16]
    const float* __restrict__ ln_beta, // [16]
    const float* __restrict__ T,       // [64,100]
    float* __restrict__ out,           // [B,64,128]
    float* __restrict__ outmask)       // [B,64] stored as float
{
    __shared__ float parts[LTOT * DIM];   // 51200 B
    __shared__ float mvec[LTOT];

    const int b   = blockIdx.x;
    const int tid = threadIdx.x;

    // ---- load gamma/beta into registers once (general path; tiny) ----
    float g[BIN], be[BIN];
    {
        const float4* G4 = reinterpret_cast<const float4*>(ln_gamma);
        const float4* B4 = reinterpret_cast<const float4*>(ln_beta);
        #pragma unroll
        for (int q = 0; q < 4; ++q) {
            float4 gv = G4[q], bv = B4[q];
            g[q*4+0] = gv.x; g[q*4+1] = gv.y; g[q*4+2] = gv.z; g[q*4+3] = gv.w;
            be[q*4+0] = bv.x; be[q*4+1] = bv.y; be[q*4+2] = bv.z; be[q*4+3] = bv.w;
        }
    }

    // ---- phase 1a: discrete embedding gather (float4, coalesced per row) ----
    {
        const int nvec = LD * (DIM / 4);   // 1600 float4 elements
        for (int e = tid; e < nvec; e += 256) {
            int l  = e >> 5;       // e / 32
            int c4 = e & 31;
            int idx = dindex[b * LD + l];
            float4 src = *reinterpret_cast<const float4*>(disc_emb + (size_t)idx * DIM + c4 * 4);
            *reinterpret_cast<float4*>(&parts[l * DIM + c4 * 4]) = src;
        }
    }

    // ---- phase 1b: continuous tokens, 2 per iteration (128 threads each) ----
    {
        const int sub = tid >> 7;      // 0 or 1
        const int dd  = tid & 127;     // output dim
        for (int l0 = 0; l0 < LC; l0 += 2) {
            int   l  = l0 + sub;
            int   ci = cindex[b * LC + l];
            float cv = cval[b * LC + l];

            // h = cv * v + b1  (vector loads of the 16-wide rows)
            float h[BIN];
            {
                const float4* V4 = reinterpret_cast<const float4*>(v_emb  + (size_t)ci * BIN);
                const float4* B14 = reinterpret_cast<const float4*>(b1_emb + (size_t)ci * BIN);
                #pragma unroll
                for (int q = 0; q < 4; ++q) {
                    float4 vv = V4[q], b1v = B14[q];
                    h[q*4+0] = cv * vv.x + b1v.x;
                    h[q*4+1] = cv * vv.y + b1v.y;
                    h[q*4+2] = cv * vv.z + b1v.z;
                    h[q*4+3] = cv * vv.w + b1v.w;
                }
            }
            float mu = 0.f;
            #pragma unroll
            for (int k = 0; k < BIN; ++k) mu += h[k];
            mu *= (1.f / BIN);
            float var = 0.f;
            #pragma unroll
            for (int k = 0; k < BIN; ++k) { float t = h[k] - mu; var += t * t; }
            var *= (1.f / BIN);
            float rstd = rsqrtf(var + LN_EPS);

            // a = relu(LN(h));  continuous_part[d] = sum_k a[k]*w[k][d] + b2[d]
            float acc = b2_emb[(size_t)ci * DIM + dd];
            const float* wrow = w_emb + (size_t)ci * (BIN * DIM) + dd;
            #pragma unroll
            for (int k = 0; k < BIN; ++k) {
                float a = (h[k] - mu) * rstd * g[k] + be[k];
                a = fmaxf(a, 0.f);
                acc += a * wrow[k * DIM];
            }
            parts[(LD + l) * DIM + dd] = acc;
        }
    }

    // ---- phase 1c: mask vector ----
    if (tid < LTOT) {
        int m = (tid < LD) ? dmask[b * LD + tid] : cmask[b * LC + (tid - LD)];
        mvec[tid] = 1.0f - (float)m;
    }

    __syncthreads();

    // ---- mask output (threads 0..63) ----
    if (tid < NO) {
        float s = 0.f;
        for (int l = 0; l < LTOT; ++l) s += T[tid * LTOT + l] * mvec[l];
        float sg = (s > 0.f) ? 1.f : ((s < 0.f) ? -1.f : 0.f);
        outmask[(size_t)b * NO + tid] = 1.f - sg;
    }

    // ---- phase 2: out[b] = T[64x100] @ parts[100x128] ----
    {
        const int wv   = __builtin_amdgcn_readfirstlane(tid >> 6); // wave id 0..3 (uniform)
        const int lane = tid & 63;
        const int d0   = lane * 2;

        float2 acc[16];
        #pragma unroll
        for (int i = 0; i < 16; ++i) { acc[i].x = 0.f; acc[i].y = 0.f; }

        for (int l4 = 0; l4 < LTOT / 4; ++l4) {
            float2 p0 = *reinterpret_cast<const float2*>(&parts[(l4*4 + 0) * DIM + d0]);
            float2 p1 = *reinterpret_cast<const float2*>(&parts[(l4*4 + 1) * DIM + d0]);
            float2 p2 = *reinterpret_cast<const float2*>(&parts[(l4*4 + 2) * DIM + d0]);
            float2 p3 = *reinterpret_cast<const float2*>(&parts[(l4*4 + 3) * DIM + d0]);
            #pragma unroll
            for (int oi = 0; oi < 16; ++oi) {
                int o = wv + oi * 4;   // o uniform per wave
                float4 t = *reinterpret_cast<const float4*>(&T[o * LTOT + l4 * 4]);
                acc[oi].x += t.x * p0.x; acc[oi].y += t.x * p0.y;
                acc[oi].x += t.y * p1.x; acc[oi].y += t.y * p1.y;
                acc[oi].x += t.z * p2.x; acc[oi].y += t.z * p2.y;
                acc[oi].x += t.w * p3.x; acc[oi].y += t.w * p3.y;
            }
        }

        float* ob = out + (size_t)b * NO * DIM;
        #pragma unroll
        for (int oi = 0; oi < 16; ++oi) {
            int o = wv + oi * 4;
            *reinterpret_cast<float2*>(&ob[o * DIM + d0]) = acc[oi];
        }
    }
}

extern "C" void kernel_launch(void* const* d_in, const int* in_sizes, int n_in,
                              void* d_out, int out_size, void* d_ws, size_t ws_size,
                              hipStream_t stream) {
    const int*   dindex  = (const int*)  d_in[0];
    const int*   dmask   = (const int*)  d_in[1];
    const float* cval    = (const float*)d_in[2];
    const int*   cindex  = (const int*)  d_in[3];
    const int*   cmask   = (const int*)  d_in[4];
    const float* disc_emb= (const float*)d_in[5];
    const float* v_emb   = (const float*)d_in[6];
    const float* b1_emb  = (const float*)d_in[7];
    const float* w_emb   = (const float*)d_in[8];
    const float* b2_emb  = (const float*)d_in[9];
    const float* lng     = (const float*)d_in[10];
    const float* lnb     = (const float*)d_in[11];
    const float* T       = (const float*)d_in[12];

    float* out     = (float*)d_out;
    float* outmask = out + (size_t)NB * NO * DIM;   // mask stored as float after main out

    hipLaunchKernelGGL(fused_embed_kernel, dim3(NB), dim3(256), 0, stream,
                       dindex, dmask, cval, cindex, cmask,
                       disc_emb, v_emb, b1_emb, w_emb, b2_emb,
                       lng, lnb, T, out, outmask);
}

// Round 2
// 376.734 us; speedup vs baseline: 1.2328x; 1.2328x over previous
//
#include <hip/hip_runtime.h>
#include <hip/hip_bf16.h>

#define NB 4096
#define LD_ 50
#define LC_ 50
#define LTOT 100
#define DIM 128
#define BIN 16
#define NO 64
#define KPAD 128
#define LP 136              // padded K-stride of PbfT in bf16 elems (272 B, 16B-multiple)
#define LN_EPS 1e-5f

typedef __attribute__((ext_vector_type(8))) short bf16x8;   // 8 bf16 = 4 VGPRs
typedef __attribute__((ext_vector_type(4))) float f32x4;

__device__ __forceinline__ unsigned short f2bf(float f) {
    return __builtin_bit_cast(unsigned short, __float2bfloat16(f));
}

// ---- pre-kernel: T [64][100] fp32 -> Tbf [64][128] bf16 (zero-padded K) ----
__global__ __launch_bounds__(256) void convT_kernel(const float* __restrict__ T,
                                                    unsigned short* __restrict__ Tbf) {
    int t = blockIdx.x * 256 + threadIdx.x;      // 0..8191
    if (t < NO * KPAD) {
        int o = t >> 7, k = t & 127;
        float v = (k < LTOT) ? T[o * LTOT + k] : 0.f;
        Tbf[t] = f2bf(v);
    }
}

__global__ __launch_bounds__(256) void fused_embed_kernel(
    const int* __restrict__ dindex,    // [B,50]
    const int* __restrict__ dmask,     // [B,50]
    const float* __restrict__ cval,    // [B,50]
    const int* __restrict__ cindex,    // [B,50]
    const int* __restrict__ cmask,     // [B,50]
    const float* __restrict__ disc_emb,// [100001,128]
    const float* __restrict__ v_emb,   // [1001,16]
    const float* __restrict__ b1_emb,  // [1001,16]
    const float* __restrict__ w_emb,   // [1001,2048]
    const float* __restrict__ b2_emb,  // [1001,128]
    const float* __restrict__ ln_gamma,// [16]
    const float* __restrict__ ln_beta, // [16]
    const float* __restrict__ T,       // [64,100] fp32 (for mask path)
    const unsigned short* __restrict__ Tbf, // [64][128] bf16
    float* __restrict__ out,           // [B,64,128]
    float* __restrict__ outmask)       // [B,64] stored as float
{
    // parts, stored TRANSPOSED in bf16: PbfT[d][l], K-stride LP
    __shared__ unsigned short PbfT[DIM * LP];     // 34816 B
    __shared__ float a_lds[LC_ * 17];             // 3400 B, stride 17 kills write conflicts
    __shared__ float buf32[8 * DIM];              // 4096 B bounce buffer
    __shared__ float mvec[LTOT];

    const int b   = blockIdx.x;
    const int tid = threadIdx.x;

    // ================= phase 0: per-token LN + ReLU activations =================
    if (tid < LC_) {
        const int l = tid;
        const int ci = cindex[b * LC_ + l];
        const float cv = cval[b * LC_ + l];
        float h[BIN];
        {
            const float4* V4  = reinterpret_cast<const float4*>(v_emb  + (size_t)ci * BIN);
            const float4* B14 = reinterpret_cast<const float4*>(b1_emb + (size_t)ci * BIN);
            #pragma unroll
            for (int q = 0; q < 4; ++q) {
                float4 vv = V4[q], b1v = B14[q];
                h[q*4+0] = cv * vv.x + b1v.x;
                h[q*4+1] = cv * vv.y + b1v.y;
                h[q*4+2] = cv * vv.z + b1v.z;
                h[q*4+3] = cv * vv.w + b1v.w;
            }
        }
        float mu = 0.f;
        #pragma unroll
        for (int k = 0; k < BIN; ++k) mu += h[k];
        mu *= (1.f / BIN);
        float var = 0.f;
        #pragma unroll
        for (int k = 0; k < BIN; ++k) { float t = h[k] - mu; var += t * t; }
        var *= (1.f / BIN);
        const float rstd = rsqrtf(var + LN_EPS);
        #pragma unroll
        for (int k = 0; k < BIN; ++k) {
            float a = (h[k] - mu) * rstd * ln_gamma[k] + ln_beta[k];
            a_lds[l * 17 + k] = fmaxf(a, 0.f);
        }
    }

    // mask vector
    if (tid < LTOT) {
        int m = (tid < LD_) ? dmask[b * LD_ + tid] : cmask[b * LC_ + (tid - LD_)];
        mvec[tid] = 1.0f - (float)m;
    }

    // zero-fill PbfT K-rows l=100..127 (K padding for the MFMA loop)
    {
        const int d  = tid & 127;
        const int hh = tid >> 7;
        unsigned short* row = &PbfT[d * LP];
        if (hh == 0) {
            #pragma unroll
            for (int q = 0; q < 4; ++q)
                *reinterpret_cast<uint2*>(&row[100 + q * 4]) = make_uint2(0u, 0u);
        } else {
            #pragma unroll
            for (int q = 0; q < 3; ++q)
                *reinterpret_cast<uint2*>(&row[116 + q * 4]) = make_uint2(0u, 0u);
        }
    }

    // ================= phase 1a: discrete gather, transposed bf16 store =========
    {
        const int d  = tid & 127;
        const int hh = tid >> 7;
        // quads of l: q = 0..11 covers l 0..47
        for (int q = hh; q < 12; q += 2) {
            const int l0 = q * 4;
            float f[4];
            #pragma unroll
            for (int j = 0; j < 4; ++j) {
                int idx = dindex[b * LD_ + l0 + j];
                f[j] = disc_emb[(size_t)idx * DIM + d];
            }
            unsigned int lo = (unsigned)f2bf(f[0]) | ((unsigned)f2bf(f[1]) << 16);
            unsigned int hi = (unsigned)f2bf(f[2]) | ((unsigned)f2bf(f[3]) << 16);
            *reinterpret_cast<uint2*>(&PbfT[d * LP + l0]) = make_uint2(lo, hi);
        }
        if (hh == 0) {  // tail l = 48,49
            float f0 = disc_emb[(size_t)dindex[b * LD_ + 48] * DIM + d];
            float f1 = disc_emb[(size_t)dindex[b * LD_ + 49] * DIM + d];
            *reinterpret_cast<unsigned int*>(&PbfT[d * LP + 48]) =
                (unsigned)f2bf(f0) | ((unsigned)f2bf(f1) << 16);
        }
    }

    __syncthreads();   // a_lds, mvec ready

    // ================= mask output =================
    if (tid < NO) {
        float s = 0.f;
        for (int l = 0; l < LTOT; ++l) s += T[tid * LTOT + l] * mvec[l];
        float sg = (s > 0.f) ? 1.f : ((s < 0.f) ? -1.f : 0.f);
        outmask[(size_t)b * NO + tid] = 1.f - sg;
    }

    // ================= phase 1b: continuous matvec =================
    const int dq = tid & 31;   // d-quad (4 floats)
    const int ts = tid >> 5;   // token slot 0..7

    // --- special pass: tokens 50,51 (l-offsets 0,1 in continuous space) ---
    if (ts < 2) {
        const int lc = ts;     // 0,1
        const int ci = cindex[b * LC_ + lc];
        float4 acc = *reinterpret_cast<const float4*>(b2_emb + (size_t)ci * DIM + dq * 4);
        #pragma unroll
        for (int k = 0; k < BIN; ++k) {
            const float a = a_lds[lc * 17 + k];
            float4 w4 = *reinterpret_cast<const float4*>(w_emb + (size_t)ci * (BIN * DIM) + k * DIM + dq * 4);
            acc.x += a * w4.x; acc.y += a * w4.y; acc.z += a * w4.z; acc.w += a * w4.w;
        }
        *reinterpret_cast<float4*>(&buf32[ts * DIM + dq * 4]) = acc;
    }
    __syncthreads();
    if (tid < 128) {
        unsigned int v = (unsigned)f2bf(buf32[tid]) | ((unsigned)f2bf(buf32[DIM + tid]) << 16);
        *reinterpret_cast<unsigned int*>(&PbfT[tid * LP + 50]) = v;
    }
    __syncthreads();

    // --- main passes: 6 passes x 8 tokens, parts rows l = 52 + 8p + ts ---
    for (int p = 0; p < 6; ++p) {
        {
            const int lc = 2 + p * 8 + ts;   // continuous index 2..49
            const int ci = cindex[b * LC_ + lc];
            float4 acc = *reinterpret_cast<const float4*>(b2_emb + (size_t)ci * DIM + dq * 4);
            #pragma unroll
            for (int k = 0; k < BIN; ++k) {
                const float a = a_lds[lc * 17 + k];
                float4 w4 = *reinterpret_cast<const float4*>(w_emb + (size_t)ci * (BIN * DIM) + k * DIM + dq * 4);
                acc.x += a * w4.x; acc.y += a * w4.y; acc.z += a * w4.z; acc.w += a * w4.w;
            }
            *reinterpret_cast<float4*>(&buf32[ts * DIM + dq * 4]) = acc;
        }
        __syncthreads();
        {
            const int d  = tid & 127;
            const int hh = tid >> 7;
            const int l0 = 52 + p * 8 + 4 * hh;   // byte offset 2*l0 is 8-aligned
            float g0 = buf32[(4*hh + 0) * DIM + d];
            float g1 = buf32[(4*hh + 1) * DIM + d];
            float g2 = buf32[(4*hh + 2) * DIM + d];
            float g3 = buf32[(4*hh + 3) * DIM + d];
            unsigned int lo = (unsigned)f2bf(g0) | ((unsigned)f2bf(g1) << 16);
            unsigned int hi = (unsigned)f2bf(g2) | ((unsigned)f2bf(g3) << 16);
            *reinterpret_cast<uint2*>(&PbfT[d * LP + l0]) = make_uint2(lo, hi);
        }
        __syncthreads();
    }

    // ================= phase 2: MFMA GEMM out[b] = T(64x100) @ parts(100x128) ====
    {
        const int w    = tid >> 6;    // wave 0..3 -> o-tile
        const int lane = tid & 63;
        const int r16  = lane & 15;
        const int g4   = lane >> 4;   // k-block 0..3

        f32x4 acc[8];
        #pragma unroll
        for (int nt = 0; nt < 8; ++nt) acc[nt] = (f32x4){0.f, 0.f, 0.f, 0.f};

        // A-fragments straight from global bf16 T (L1/L2-resident, 16 KB)
        bf16x8 afr[4];
        const unsigned short* Ta = Tbf + (16 * w + r16) * KPAD + g4 * 8;
        #pragma unroll
        for (int kc = 0; kc < 4; ++kc)
            afr[kc] = *reinterpret_cast<const bf16x8*>(Ta + kc * 32);

        #pragma unroll
        for (int nt = 0; nt < 8; ++nt) {
            const unsigned short* Bp = &PbfT[(nt * 16 + r16) * LP + g4 * 8];
            #pragma unroll
            for (int kc = 0; kc < 4; ++kc) {
                bf16x8 bfr = *reinterpret_cast<const bf16x8*>(Bp + kc * 32);
                acc[nt] = __builtin_amdgcn_mfma_f32_16x16x32_bf16(afr[kc], bfr, acc[nt], 0, 0, 0);
            }
        }

        // C layout: col = lane&15 (d), row = 4*(lane>>4)+reg (o within tile)
        float* ob = out + (size_t)b * NO * DIM + (size_t)(16 * w) * DIM;
        #pragma unroll
        for (int nt = 0; nt < 8; ++nt) {
            #pragma unroll
            for (int r = 0; r < 4; ++r) {
                ob[(g4 * 4 + r) * DIM + nt * 16 + r16] = acc[nt][r];
            }
        }
    }
}

extern "C" void kernel_launch(void* const* d_in, const int* in_sizes, int n_in,
                              void* d_out, int out_size, void* d_ws, size_t ws_size,
                              hipStream_t stream) {
    const int*   dindex  = (const int*)  d_in[0];
    const int*   dmask   = (const int*)  d_in[1];
    const float* cval    = (const float*)d_in[2];
    const int*   cindex  = (const int*)  d_in[3];
    const int*   cmask   = (const int*)  d_in[4];
    const float* disc_emb= (const float*)d_in[5];
    const float* v_emb   = (const float*)d_in[6];
    const float* b1_emb  = (const float*)d_in[7];
    const float* w_emb   = (const float*)d_in[8];
    const float* b2_emb  = (const float*)d_in[9];
    const float* lng     = (const float*)d_in[10];
    const float* lnb     = (const float*)d_in[11];
    const float* T       = (const float*)d_in[12];

    float* out     = (float*)d_out;
    float* outmask = out + (size_t)NB * NO * DIM;

    unsigned short* Tbf = (unsigned short*)d_ws;   // 16 KB scratch

    hipLaunchKernelGGL(convT_kernel, dim3((NO * KPAD + 255) / 256), dim3(256), 0, stream, T, Tbf);
    hipLaunchKernelGGL(fused_embed_kernel, dim3(NB), dim3(256), 0, stream,
                       dindex, dmask, cval, cindex, cmask,
                       disc_emb, v_emb, b1_emb, w_emb, b2_emb,
                       lng, lnb, T, Tbf, out, outmask);
}

// Round 5
// 323.509 us; speedup vs baseline: 1.4357x; 1.1645x over previous
//
#include <hip/hip_runtime.h>
#include <hip/hip_bf16.h>

#define NB 4096
#define LD_ 50
#define LC_ 50
#define LTOT 100
#define DIM 128
#define BIN 16
#define NO 64
#define KPAD 128
#define LP 136              // padded K-stride of PbfT in bf16 elems (272 B)
#define LN_EPS 1e-5f

typedef __attribute__((ext_vector_type(8))) short bf16x8;   // 8 bf16 = 4 VGPRs
typedef __attribute__((ext_vector_type(4))) float f32x4;

__device__ __forceinline__ unsigned short f2bf(float f) {
    return __builtin_bit_cast(unsigned short, __float2bfloat16(f));
}
__device__ __forceinline__ float bf2f(unsigned u16) {   // low 16 bits = bf16
    return __builtin_bit_cast(float, u16 << 16);
}

// ---- pre-kernel A: w_emb [1001*2048] fp32 -> bf16 (packed) ----
__global__ __launch_bounds__(256) void convW_kernel(const float* __restrict__ w,
                                                    unsigned short* __restrict__ wbf) {
    int t = blockIdx.x * 256 + threadIdx.x;     // 0..512511, exactly 2002 blocks
    float4 v = *reinterpret_cast<const float4*>(w + (size_t)t * 4);
    unsigned lo = (unsigned)f2bf(v.x) | ((unsigned)f2bf(v.y) << 16);
    unsigned hi = (unsigned)f2bf(v.z) | ((unsigned)f2bf(v.w) << 16);
    *reinterpret_cast<uint2*>(wbf + (size_t)t * 4) = make_uint2(lo, hi);
}

// ---- pre-kernel B: T [64][100] fp32 -> Tbf [64][128] bf16 (zero-padded K) ----
__global__ __launch_bounds__(256) void convT_kernel(const float* __restrict__ T,
                                                    unsigned short* __restrict__ Tbf) {
    int t = blockIdx.x * 256 + threadIdx.x;
    if (t < NO * KPAD) {
        int o = t >> 7, k = t & 127;
        float v = (k < LTOT) ? T[o * LTOT + k] : 0.f;
        Tbf[t] = f2bf(v);
    }
}

__global__ __launch_bounds__(256) void fused_embed_kernel(
    const int* __restrict__ dindex,    // [B,50]
    const int* __restrict__ dmask,     // [B,50]
    const float* __restrict__ cval,    // [B,50]
    const int* __restrict__ cindex,    // [B,50]
    const int* __restrict__ cmask,     // [B,50]
    const float* __restrict__ disc_emb,// [100001,128] fp32
    const float* __restrict__ v_emb,   // [1001,16]
    const float* __restrict__ b1_emb,  // [1001,16]
    const unsigned short* __restrict__ w_bf, // [1001,2048] bf16
    const float* __restrict__ b2_emb,  // [1001,128]
    const float* __restrict__ ln_gamma,// [16]
    const float* __restrict__ ln_beta, // [16]
    const float* __restrict__ T,       // [64,100] fp32 (mask path)
    const unsigned short* __restrict__ Tbf, // [64][128] bf16
    float* __restrict__ out,           // [B,64,128]
    float* __restrict__ outmask)       // [B,64] as float
{
    __shared__ unsigned short PbfT[DIM * LP];   // 34816 B, parts transposed [d][l]
    __shared__ float buf32[4][2][DIM];          // 4096 B, per-wave bounce
    __shared__ float mvec[LTOT];                // 400 B
    // total ~39.3 KB -> 4 blocks/CU

    const int b    = blockIdx.x;
    const int tid  = threadIdx.x;
    const int wave = tid >> 6;        // 0..3 (wave-uniform)
    const int lane = tid & 63;

    // ---- mask vector (pre-barrier) ----
    if (tid < LTOT) {
        int m = (tid < LD_) ? dmask[b * LD_ + tid] : cmask[b * LC_ + (tid - LD_)];
        mvec[tid] = 1.0f - (float)m;
    }

    // ---- zero-fill K-pad rows l=100..127 ----
    {
        const int d  = tid & 127;
        const int hh = tid >> 7;
        unsigned short* row = &PbfT[d * LP];
        if (hh == 0) {
            #pragma unroll
            for (int q = 0; q < 4; ++q)
                *reinterpret_cast<uint2*>(&row[100 + q * 4]) = make_uint2(0u, 0u);
        } else {
            #pragma unroll
            for (int q = 0; q < 3; ++q)
                *reinterpret_cast<uint2*>(&row[116 + q * 4]) = make_uint2(0u, 0u);
        }
    }

    // ---- phase 1a: discrete gather (fp32 scalar, d-contiguous), transposed store ----
    {
        const int d  = tid & 127;
        const int hh = tid >> 7;
        for (int q = hh; q < 12; q += 2) {
            const int l0 = q * 4;
            float f[4];
            #pragma unroll
            for (int j = 0; j < 4; ++j) {
                int idx = dindex[b * LD_ + l0 + j];
                f[j] = disc_emb[(size_t)idx * DIM + d];
            }
            unsigned lo = (unsigned)f2bf(f[0]) | ((unsigned)f2bf(f[1]) << 16);
            unsigned hi = (unsigned)f2bf(f[2]) | ((unsigned)f2bf(f[3]) << 16);
            *reinterpret_cast<uint2*>(&PbfT[d * LP + l0]) = make_uint2(lo, hi);
        }
        if (hh == 0) {  // tail l = 48,49
            float f0 = disc_emb[(size_t)dindex[b * LD_ + 48] * DIM + d];
            float f1 = disc_emb[(size_t)dindex[b * LD_ + 49] * DIM + d];
            *reinterpret_cast<unsigned int*>(&PbfT[d * LP + 48]) =
                (unsigned)f2bf(f0) | ((unsigned)f2bf(f1) << 16);
        }
    }

    // ---- phase 1b: continuous tokens — wave-autonomous, NO barriers ----
    // wave handles token pairs p = wave, wave+4, ...  (tokens 2p, 2p+1)
    {
        const int th = lane >> 5;     // which token of the pair
        const int q  = lane & 31;     // dim-quad within token
        const int bcast = lane & 32;  // shuffle broadcast base

        for (int p = wave; p < 25; p += 4) {
            const int t  = p * 2 + th;
            const int ci = cindex[b * LC_ + t];
            const float cv = cval[b * LC_ + t];

            // LN on lanes q<16 (one bin per lane), 16-lane shuffle reduce
            float a_val = 0.f;
            if (q < 16) {
                float h = cv * v_emb[ci * BIN + q] + b1_emb[ci * BIN + q];
                float s = h;
                s += __shfl_xor(s, 1, 16);
                s += __shfl_xor(s, 2, 16);
                s += __shfl_xor(s, 4, 16);
                s += __shfl_xor(s, 8, 16);
                float mu = s * (1.f / BIN);
                float e  = h - mu;
                float v2 = e * e;
                v2 += __shfl_xor(v2, 1, 16);
                v2 += __shfl_xor(v2, 2, 16);
                v2 += __shfl_xor(v2, 4, 16);
                v2 += __shfl_xor(v2, 8, 16);
                float rstd = rsqrtf(v2 * (1.f / BIN) + LN_EPS);
                a_val = fmaxf(e * rstd * ln_gamma[q] + ln_beta[q], 0.f);
            }

            // matvec: acc[4 dims] = b2 + sum_k a_k * w[ci][k][dims]
            float4 acc = *reinterpret_cast<const float4*>(b2_emb + (size_t)ci * DIM + q * 4);
            const uint2* wp = reinterpret_cast<const uint2*>(w_bf + (size_t)ci * (BIN * DIM) + q * 4);
            #pragma unroll
            for (int k = 0; k < BIN; ++k) {
                float ak = __shfl(a_val, bcast + k);
                uint2 wv = wp[k * 32];          // 4 bf16 at dims q*4..q*4+3
                acc.x += ak * bf2f(wv.x & 0xffffu);
                acc.y += ak * bf2f(wv.x >> 16);
                acc.z += ak * bf2f(wv.y & 0xffffu);
                acc.w += ak * bf2f(wv.y >> 16);
            }

            // per-wave LDS bounce transpose (intra-wave ordering only)
            *reinterpret_cast<float4*>(&buf32[wave][th][q * 4]) = acc;
            __builtin_amdgcn_wave_barrier();   // keep compiler from reordering ds ops
            float x0 = buf32[wave][0][lane];
            float x1 = buf32[wave][1][lane];
            float x2 = buf32[wave][0][lane + 64];
            float x3 = buf32[wave][1][lane + 64];
            __builtin_amdgcn_wave_barrier();
            const int l0 = 50 + p * 2;
            *reinterpret_cast<unsigned int*>(&PbfT[lane * LP + l0]) =
                (unsigned)f2bf(x0) | ((unsigned)f2bf(x1) << 16);
            *reinterpret_cast<unsigned int*>(&PbfT[(lane + 64) * LP + l0]) =
                (unsigned)f2bf(x2) | ((unsigned)f2bf(x3) << 16);
        }
    }

    __syncthreads();   // ONE barrier: PbfT + mvec complete

    // ---- mask output ----
    if (tid < NO) {
        float s = 0.f;
        for (int l = 0; l < LTOT; ++l) s += T[tid * LTOT + l] * mvec[l];
        float sg = (s > 0.f) ? 1.f : ((s < 0.f) ? -1.f : 0.f);
        outmask[(size_t)b * NO + tid] = 1.f - sg;
    }

    // ---- phase 2: MFMA GEMM out[b] = T(64x128K) @ parts(128Kx128) ----
    {
        const int r16 = lane & 15;
        const int g4  = lane >> 4;    // k-block

        f32x4 acc[8];
        #pragma unroll
        for (int nt = 0; nt < 8; ++nt) acc[nt] = (f32x4){0.f, 0.f, 0.f, 0.f};

        bf16x8 afr[4];
        const unsigned short* Ta = Tbf + (16 * wave + r16) * KPAD + g4 * 8;
        #pragma unroll
        for (int kc = 0; kc < 4; ++kc)
            afr[kc] = *reinterpret_cast<const bf16x8*>(Ta + kc * 32);

        #pragma unroll
        for (int nt = 0; nt < 8; ++nt) {
            const unsigned short* Bp = &PbfT[(nt * 16 + r16) * LP + g4 * 8];
            #pragma unroll
            for (int kc = 0; kc < 4; ++kc) {
                bf16x8 bfr = *reinterpret_cast<const bf16x8*>(Bp + kc * 32);
                acc[nt] = __builtin_amdgcn_mfma_f32_16x16x32_bf16(afr[kc], bfr, acc[nt], 0, 0, 0);
            }
        }

        float* ob = out + (size_t)b * NO * DIM + (size_t)(16 * wave) * DIM;
        #pragma unroll
        for (int nt = 0; nt < 8; ++nt) {
            #pragma unroll
            for (int r = 0; r < 4; ++r) {
                ob[(g4 * 4 + r) * DIM + nt * 16 + r16] = acc[nt][r];
            }
        }
    }
}

extern "C" void kernel_launch(void* const* d_in, const int* in_sizes, int n_in,
                              void* d_out, int out_size, void* d_ws, size_t ws_size,
                              hipStream_t stream) {
    const int*   dindex  = (const int*)  d_in[0];
    const int*   dmask   = (const int*)  d_in[1];
    const float* cval    = (const float*)d_in[2];
    const int*   cindex  = (const int*)  d_in[3];
    const int*   cmask   = (const int*)  d_in[4];
    const float* disc_emb= (const float*)d_in[5];
    const float* v_emb   = (const float*)d_in[6];
    const float* b1_emb  = (const float*)d_in[7];
    const float* w_emb   = (const float*)d_in[8];
    const float* b2_emb  = (const float*)d_in[9];
    const float* lng     = (const float*)d_in[10];
    const float* lnb     = (const float*)d_in[11];
    const float* T       = (const float*)d_in[12];

    float* out     = (float*)d_out;
    float* outmask = out + (size_t)NB * NO * DIM;

    unsigned short* w_bf = (unsigned short*)d_ws;                 // 4,100,096 B
    unsigned short* Tbf  = (unsigned short*)((char*)d_ws + 4100096); // 16 KB

    hipLaunchKernelGGL(convW_kernel, dim3(2002), dim3(256), 0, stream, w_emb, w_bf);
    hipLaunchKernelGGL(convT_kernel, dim3(32), dim3(256), 0, stream, T, Tbf);
    hipLaunchKernelGGL(fused_embed_kernel, dim3(NB), dim3(256), 0, stream,
                       dindex, dmask, cval, cindex, cmask,
                       disc_emb, v_emb, b1_emb, w_bf, b2_emb,
                       lng, lnb, T, Tbf, out, outmask);
}

// Round 6
// 322.444 us; speedup vs baseline: 1.4404x; 1.0033x over previous
//
#include <hip/hip_runtime.h>
#include <hip/hip_bf16.h>

#define NB 4096
#define LD_ 50
#define LC_ 50
#define LTOT 100
#define DIM 128
#define BIN 16
#define NO 64
#define KPAD 128
#define LP 136              // padded K-stride of PbfT in bf16 elems (272 B = 16*17)
#define LN_EPS 1e-5f

// conv_all grid split
#define DISC_ELEMS 12800128   // 100001*128
#define DISC_VEC8  1600016    // DISC_ELEMS/8
#define DISC_BLKS  6251       // ceil(DISC_VEC8/256)
#define W_VEC8     256256     // 1001*2048/8
#define W_BLKS     1001
#define T_BLKS     32         // 8192 elems, 1/thread
#define CONV_BLKS  (DISC_BLKS + W_BLKS + T_BLKS)

typedef __attribute__((ext_vector_type(8))) short bf16x8;   // 8 bf16 = 4 VGPRs
typedef __attribute__((ext_vector_type(4))) float f32x4;

__device__ __forceinline__ unsigned f2bf(float f) {
    return (unsigned)__builtin_bit_cast(unsigned short, __float2bfloat16(f));
}
__device__ __forceinline__ float bf2f(unsigned u16) {   // low 16 bits = bf16
    return __builtin_bit_cast(float, u16 << 16);
}

// ---- single pre-kernel: disc_emb, w_emb -> bf16; T -> bf16 zero-padded ----
__global__ __launch_bounds__(256) void conv_all(const float* __restrict__ disc,
                                                const float* __restrict__ w,
                                                const float* __restrict__ T,
                                                unsigned short* __restrict__ disc_bf,
                                                unsigned short* __restrict__ w_bf,
                                                unsigned short* __restrict__ Tbf) {
    const int bb = blockIdx.x;
    if (bb < DISC_BLKS) {
        size_t v = (size_t)bb * 256 + threadIdx.x;
        if (v < DISC_VEC8) {
            const float4* src = reinterpret_cast<const float4*>(disc + v * 8);
            float4 a = src[0], c = src[1];
            uint4 o;
            o.x = f2bf(a.x) | (f2bf(a.y) << 16);
            o.y = f2bf(a.z) | (f2bf(a.w) << 16);
            o.z = f2bf(c.x) | (f2bf(c.y) << 16);
            o.w = f2bf(c.z) | (f2bf(c.w) << 16);
            *reinterpret_cast<uint4*>(disc_bf + v * 8) = o;
        }
    } else if (bb < DISC_BLKS + W_BLKS) {
        size_t v = (size_t)(bb - DISC_BLKS) * 256 + threadIdx.x;   // < W_VEC8 exact
        const float4* src = reinterpret_cast<const float4*>(w + v * 8);
        float4 a = src[0], c = src[1];
        uint4 o;
        o.x = f2bf(a.x) | (f2bf(a.y) << 16);
        o.y = f2bf(a.z) | (f2bf(a.w) << 16);
        o.z = f2bf(c.x) | (f2bf(c.y) << 16);
        o.w = f2bf(c.z) | (f2bf(c.w) << 16);
        *reinterpret_cast<uint4*>(w_bf + v * 8) = o;
    } else {
        int t = (bb - DISC_BLKS - W_BLKS) * 256 + threadIdx.x;     // 0..8191
        int o = t >> 7, k = t & 127;
        float v = (k < LTOT) ? T[o * LTOT + k] : 0.f;
        Tbf[t] = (unsigned short)f2bf(v);
    }
}

__global__ __launch_bounds__(512, 6) void fused_embed_kernel(
    const int* __restrict__ dindex,    // [B,50]
    const int* __restrict__ dmask,     // [B,50]
    const float* __restrict__ cval,    // [B,50]
    const int* __restrict__ cindex,    // [B,50]
    const int* __restrict__ cmask,     // [B,50]
    const unsigned short* __restrict__ disc_bf, // [100001,128] bf16
    const float* __restrict__ v_emb,   // [1001,16]
    const float* __restrict__ b1_emb,  // [1001,16]
    const unsigned short* __restrict__ w_bf, // [1001,2048] bf16
    const float* __restrict__ b2_emb,  // [1001,128]
    const float* __restrict__ ln_gamma,// [16]
    const float* __restrict__ ln_beta, // [16]
    const float* __restrict__ T,       // [64,100] fp32 (mask path)
    const unsigned short* __restrict__ Tbf, // [64][128] bf16
    float* __restrict__ out,           // [B,64,128]
    float* __restrict__ outmask)       // [B,64] as float
{
    __shared__ unsigned short PbfT[DIM * LP];   // 34816 B, parts transposed [d][l]
    __shared__ float buf32[8][2][DIM];          // 8192 B, per-wave bounce
    __shared__ float mvec[LTOT];                // 400 B
    // total 43408 B -> 3 blocks/CU (24 waves = 75% cap)

    const int b    = blockIdx.x;
    const int tid  = threadIdx.x;
    const int wave = tid >> 6;        // 0..7 (wave-uniform)
    const int lane = tid & 63;
    const int d    = tid & 127;       // dim for gather phases
    const int hh   = tid >> 7;        // 0..3 (wave-uniform: hh = wave>>1)

    // ---- mask vector ----
    if (tid < LTOT) {
        int m = (tid < LD_) ? dmask[b * LD_ + tid] : cmask[b * LC_ + (tid - LD_)];
        mvec[tid] = 1.0f - (float)m;
    }

    // ---- zero-fill K-pad rows l=100..127 (7 uint2 per d, split over hh) ----
    {
        unsigned short* row = &PbfT[d * LP];
        if (hh < 3) {
            *reinterpret_cast<uint2*>(&row[100 + hh * 8])     = make_uint2(0u, 0u);
            *reinterpret_cast<uint2*>(&row[100 + hh * 8 + 4]) = make_uint2(0u, 0u);
        } else {
            *reinterpret_cast<uint2*>(&row[124]) = make_uint2(0u, 0u);
        }
    }

    // ---- phase 1a: discrete gather from bf16 table, all loads in flight ----
    {
        // this thread's 12 rows: quads q = hh, hh+4, hh+8  (l0 = 4q)
        int idxs[12];
        #pragma unroll
        for (int i = 0; i < 3; ++i) {
            const int l0 = (hh + 4 * i) * 4;
            #pragma unroll
            for (int j = 0; j < 4; ++j)
                idxs[i * 4 + j] = dindex[b * LD_ + l0 + j];
        }
        int it0 = 0, it1 = 0;
        if (hh == 0) { it0 = dindex[b * LD_ + 48]; it1 = dindex[b * LD_ + 49]; }

        unsigned short u[12];
        #pragma unroll
        for (int i = 0; i < 12; ++i)
            u[i] = disc_bf[(size_t)idxs[i] * DIM + d];
        unsigned short ut0 = 0, ut1 = 0;
        if (hh == 0) {
            ut0 = disc_bf[(size_t)it0 * DIM + d];
            ut1 = disc_bf[(size_t)it1 * DIM + d];
        }

        #pragma unroll
        for (int i = 0; i < 3; ++i) {
            const int l0 = (hh + 4 * i) * 4;
            unsigned lo = (unsigned)u[i*4+0] | ((unsigned)u[i*4+1] << 16);
            unsigned hi = (unsigned)u[i*4+2] | ((unsigned)u[i*4+3] << 16);
            *reinterpret_cast<uint2*>(&PbfT[d * LP + l0]) = make_uint2(lo, hi);
        }
        if (hh == 0) {
            *reinterpret_cast<unsigned int*>(&PbfT[d * LP + 48]) =
                (unsigned)ut0 | ((unsigned)ut1 << 16);
        }
    }

    // ---- phase 1b: continuous tokens — wave-autonomous ----
    // wave handles pairs p = wave + 8j, j = 0..3 (25 pairs total)
    {
        const int th    = lane >> 5;     // token of the pair
        const int q     = lane & 31;     // dim-quad
        const int bcast = lane & 32;     // shuffle broadcast base

        // prefetch all indices/values for this wave's pairs
        int   ci[4];
        float cv[4];
        #pragma unroll
        for (int j = 0; j < 4; ++j) {
            const int p = wave + 8 * j;
            if (p < 25) {
                const int t = p * 2 + th;
                ci[j] = cindex[b * LC_ + t];
                cv[j] = cval[b * LC_ + t];
            }
        }

        #pragma unroll
        for (int j = 0; j < 4; ++j) {
            const int p = wave + 8 * j;
            if (p >= 25) break;
            const int   c  = ci[j];
            const float v0 = cv[j];

            // LN on lanes q<16 (one bin per lane), 16-lane shuffle reduce
            float a_val = 0.f;
            if (q < 16) {
                float h = v0 * v_emb[c * BIN + q] + b1_emb[c * BIN + q];
                float s = h;
                s += __shfl_xor(s, 1, 16);
                s += __shfl_xor(s, 2, 16);
                s += __shfl_xor(s, 4, 16);
                s += __shfl_xor(s, 8, 16);
                float mu = s * (1.f / BIN);
                float e  = h - mu;
                float v2 = e * e;
                v2 += __shfl_xor(v2, 1, 16);
                v2 += __shfl_xor(v2, 2, 16);
                v2 += __shfl_xor(v2, 4, 16);
                v2 += __shfl_xor(v2, 8, 16);
                float rstd = rsqrtf(v2 * (1.f / BIN) + LN_EPS);
                a_val = fmaxf(e * rstd * ln_gamma[q] + ln_beta[q], 0.f);
            }

            // matvec: acc[4 dims] = b2 + sum_k a_k * w[c][k][dims]
            float4 acc = *reinterpret_cast<const float4*>(b2_emb + (size_t)c * DIM + q * 4);
            const uint2* wp = reinterpret_cast<const uint2*>(w_bf + (size_t)c * (BIN * DIM) + q * 4);
            #pragma unroll
            for (int k = 0; k < BIN; ++k) {
                float ak = __shfl(a_val, bcast + k);
                uint2 wv = wp[k * 32];
                acc.x += ak * bf2f(wv.x & 0xffffu);
                acc.y += ak * bf2f(wv.x >> 16);
                acc.z += ak * bf2f(wv.y & 0xffffu);
                acc.w += ak * bf2f(wv.y >> 16);
            }

            // per-wave LDS bounce transpose (intra-wave ordering only)
            *reinterpret_cast<float4*>(&buf32[wave][th][q * 4]) = acc;
            __builtin_amdgcn_wave_barrier();
            float x0 = buf32[wave][0][lane];
            float x1 = buf32[wave][1][lane];
            float x2 = buf32[wave][0][lane + 64];
            float x3 = buf32[wave][1][lane + 64];
            __builtin_amdgcn_wave_barrier();
            const int l0 = 50 + p * 2;
            *reinterpret_cast<unsigned int*>(&PbfT[lane * LP + l0]) =
                f2bf(x0) | (f2bf(x1) << 16);
            *reinterpret_cast<unsigned int*>(&PbfT[(lane + 64) * LP + l0]) =
                f2bf(x2) | (f2bf(x3) << 16);
        }
    }

    __syncthreads();   // ONE barrier: PbfT + mvec complete

    // ---- mask output ----
    if (tid < NO) {
        float s = 0.f;
        for (int l = 0; l < LTOT; ++l) s += T[tid * LTOT + l] * mvec[l];
        float sg = (s > 0.f) ? 1.f : ((s < 0.f) ? -1.f : 0.f);
        outmask[(size_t)b * NO + tid] = 1.f - sg;
    }

    // ---- phase 2: MFMA GEMM, 8 waves: (o-tile = wave>>1, n-half = wave&1) ----
    {
        const int ot  = wave >> 1;    // 0..3: o rows 16*ot..+16
        const int nh  = wave & 1;     // 0..1: d cols nh*64..+64
        const int r16 = lane & 15;
        const int g4  = lane >> 4;    // k-block

        f32x4 acc[4];
        #pragma unroll
        for (int nt = 0; nt < 4; ++nt) acc[nt] = (f32x4){0.f, 0.f, 0.f, 0.f};

        bf16x8 afr[4];
        const unsigned short* Ta = Tbf + (16 * ot + r16) * KPAD + g4 * 8;
        #pragma unroll
        for (int kc = 0; kc < 4; ++kc)
            afr[kc] = *reinterpret_cast<const bf16x8*>(Ta + kc * 32);

        #pragma unroll
        for (int nt = 0; nt < 4; ++nt) {
            const unsigned short* Bp = &PbfT[((nh * 4 + nt) * 16 + r16) * LP + g4 * 8];
            #pragma unroll
            for (int kc = 0; kc < 4; ++kc) {
                bf16x8 bfr = *reinterpret_cast<const bf16x8*>(Bp + kc * 32);
                acc[nt] = __builtin_amdgcn_mfma_f32_16x16x32_bf16(afr[kc], bfr, acc[nt], 0, 0, 0);
            }
        }

        // C layout: col = lane&15 (d within 16), row = 4*(lane>>4)+reg (o within tile)
        float* ob = out + (size_t)b * NO * DIM + (size_t)(16 * ot) * DIM + nh * 64;
        #pragma unroll
        for (int nt = 0; nt < 4; ++nt) {
            #pragma unroll
            for (int r = 0; r < 4; ++r) {
                ob[(g4 * 4 + r) * DIM + nt * 16 + r16] = acc[nt][r];
            }
        }
    }
}

extern "C" void kernel_launch(void* const* d_in, const int* in_sizes, int n_in,
                              void* d_out, int out_size, void* d_ws, size_t ws_size,
                              hipStream_t stream) {
    const int*   dindex  = (const int*)  d_in[0];
    const int*   dmask   = (const int*)  d_in[1];
    const float* cval    = (const float*)d_in[2];
    const int*   cindex  = (const int*)  d_in[3];
    const int*   cmask   = (const int*)  d_in[4];
    const float* disc_emb= (const float*)d_in[5];
    const float* v_emb   = (const float*)d_in[6];
    const float* b1_emb  = (const float*)d_in[7];
    const float* w_emb   = (const float*)d_in[8];
    const float* b2_emb  = (const float*)d_in[9];
    const float* lng     = (const float*)d_in[10];
    const float* lnb     = (const float*)d_in[11];
    const float* T       = (const float*)d_in[12];

    float* out     = (float*)d_out;
    float* outmask = out + (size_t)NB * NO * DIM;

    // workspace layout (bytes): disc_bf 25,600,256 | w_bf 4,100,096 | Tbf 16,384
    unsigned short* disc_bf = (unsigned short*)d_ws;
    unsigned short* w_bf    = (unsigned short*)((char*)d_ws + 25600256);
    unsigned short* Tbf     = (unsigned short*)((char*)d_ws + 25600256 + 4100096);

    hipLaunchKernelGGL(conv_all, dim3(CONV_BLKS), dim3(256), 0, stream,
                       disc_emb, w_emb, T, disc_bf, w_bf, Tbf);
    hipLaunchKernelGGL(fused_embed_kernel, dim3(NB), dim3(512), 0, stream,
                       dindex, dmask, cval, cindex, cmask,
                       disc_bf, v_emb, b1_emb, w_bf, b2_emb,
                       lng, lnb, T, Tbf, out, outmask);
}